// Round 1
// baseline (216.681 us; speedup 1.0000x reference)
//
#include <hip/hip_runtime.h>

// Spatial transformer: affine grid (scale s, translate tx,ty) + bilinear
// sampling with zero padding.
//   x:       (1024, 1, 192, 192) f32
//   z_where: (1024, 3)           f32   [s, tx, ty]
//   out:     (1024, 1, 96, 96)   f32
//
// Memory-bound: ~37.7 MB written + gathered reads. One thread per output
// pixel; 36 blocks x 256 threads per image so the image index (and hence the
// z_where load) is workgroup-uniform -> scalar loads.

#define H_IN   192
#define W_IN   192
#define H_OUT  96
#define W_OUT  96
#define PX_PER_IMG   (H_OUT * W_OUT)       // 9216
#define BLOCK        256
#define BLOCKS_PER_IMG (PX_PER_IMG / BLOCK) // 36

__global__ __launch_bounds__(BLOCK) void st_bilinear_kernel(
    const float* __restrict__ x,
    const float* __restrict__ zw,
    float* __restrict__ out)
{
    const int b = blockIdx.x / BLOCKS_PER_IMG;              // uniform per block
    const int p = (blockIdx.x % BLOCKS_PER_IMG) * BLOCK + threadIdx.x; // < 9216
    const int oy = p / W_OUT;
    const int ox = p - oy * W_OUT;

    // z_where — uniform per block, becomes s_load
    const float s  = zw[b * 3 + 0];
    const float tx = zw[b * 3 + 1];
    const float ty = zw[b * 3 + 2];

    // affine grid, matching reference arithmetic:
    //   xs = 2*(ox+0.5)/Wo - 1 ;  gx = s*xs + tx
    const float xs = 2.0f * ((float)ox + 0.5f) / (float)W_OUT - 1.0f;
    const float ys = 2.0f * ((float)oy + 0.5f) / (float)H_OUT - 1.0f;
    const float gx = s * xs + tx;
    const float gy = s * ys + ty;

    // to input pixel coords
    const float ix = ((gx + 1.0f) * (float)W_IN - 1.0f) * 0.5f;
    const float iy = ((gy + 1.0f) * (float)H_IN - 1.0f) * 0.5f;

    const float ix0f = floorf(ix);
    const float iy0f = floorf(iy);
    const float wx1 = ix - ix0f;
    const float wy1 = iy - iy0f;
    const float wx0 = 1.0f - wx1;
    const float wy0 = 1.0f - wy1;

    const int ix0 = (int)ix0f;
    const int iy0 = (int)iy0f;
    const int ix1 = ix0 + 1;
    const int iy1 = iy0 + 1;

    const float* __restrict__ img = x + (size_t)b * (H_IN * W_IN);

    auto samp = [&](int yi, int xi) -> float {
        const bool valid = (yi >= 0) & (yi < H_IN) & (xi >= 0) & (xi < W_IN);
        const int yc = min(max(yi, 0), H_IN - 1);
        const int xc = min(max(xi, 0), W_IN - 1);
        const float v = img[yc * W_IN + xc];
        return valid ? v : 0.0f;
    };

    const float v00 = samp(iy0, ix0);
    const float v01 = samp(iy0, ix1);
    const float v10 = samp(iy1, ix0);
    const float v11 = samp(iy1, ix1);

    out[(size_t)b * PX_PER_IMG + p] =
        wy0 * wx0 * v00 + wy0 * wx1 * v01 +
        wy1 * wx0 * v10 + wy1 * wx1 * v11;
}

extern "C" void kernel_launch(void* const* d_in, const int* in_sizes, int n_in,
                              void* d_out, int out_size, void* d_ws, size_t ws_size,
                              hipStream_t stream) {
    const float* x  = (const float*)d_in[0];
    const float* zw = (const float*)d_in[1];
    float* out = (float*)d_out;

    const int B = in_sizes[1] / 3;                 // 1024
    const int grid = B * BLOCKS_PER_IMG;           // 36864 blocks
    st_bilinear_kernel<<<grid, BLOCK, 0, stream>>>(x, zw, out);
}

// Round 2
// 210.869 us; speedup vs baseline: 1.0276x; 1.0276x over previous
//
#include <hip/hip_runtime.h>

// Spatial transformer: affine grid (scale s, translate tx,ty) + bilinear
// sampling with zero padding.
//   x:       (1024, 1, 192, 192) f32
//   z_where: (1024, 3)           f32   [s, tx, ty]
//   out:     (1024, 1, 96, 96)   f32
//
// R2: 4 output px per thread (quad along x; 96%4==0 so a quad never crosses
// a row), float4 store, y-interpolation computed once per thread, 16
// independent gathers for ILP. Waves: 147k -> 37k.

#define H_IN   192
#define W_IN   192
#define H_OUT  96
#define W_OUT  96
#define PX_PER_IMG     (H_OUT * W_OUT)            // 9216
#define BLOCK          256
#define PX_PER_THREAD  4
#define PX_PER_BLOCK   (BLOCK * PX_PER_THREAD)    // 1024
#define BLOCKS_PER_IMG (PX_PER_IMG / PX_PER_BLOCK) // 9

__global__ __launch_bounds__(BLOCK) void st_bilinear_x4_kernel(
    const float* __restrict__ x,
    const float* __restrict__ zw,
    float* __restrict__ out)
{
    const int b    = blockIdx.x / BLOCKS_PER_IMG;              // block-uniform
    const int tile = blockIdx.x % BLOCKS_PER_IMG;
    const int p    = tile * PX_PER_BLOCK + threadIdx.x * PX_PER_THREAD;
    const int oy   = p / W_OUT;
    const int ox   = p - oy * W_OUT;                           // multiple of 4

    // z_where — uniform per block -> scalar loads
    const float s  = zw[b * 3 + 0];
    const float tx = zw[b * 3 + 1];
    const float ty = zw[b * 3 + 2];

    // ---- y interpolation (shared by all 4 px of the quad) ----
    const float ys  = 2.0f * ((float)oy + 0.5f) / (float)H_OUT - 1.0f;
    const float gy  = s * ys + ty;
    const float iy  = ((gy + 1.0f) * (float)H_IN - 1.0f) * 0.5f;
    const float iy0f = floorf(iy);
    const float wy1 = iy - iy0f;
    const float wy0 = 1.0f - wy1;
    const int   iy0 = (int)iy0f;
    const int   iy1 = iy0 + 1;
    const bool  y0v = (unsigned)iy0 < (unsigned)H_IN;
    const bool  y1v = (unsigned)iy1 < (unsigned)H_IN;

    const float* __restrict__ img = x + (size_t)b * (H_IN * W_IN);
    const float* __restrict__ r0  = img + min(max(iy0, 0), H_IN - 1) * W_IN;
    const float* __restrict__ r1  = img + min(max(iy1, 0), H_IN - 1) * W_IN;

    // ---- per-pixel x taps: compute all indices/weights, then issue all
    //      16 loads back-to-back (ILP), then combine ----
    float wx0[PX_PER_THREAD], wx1[PX_PER_THREAD];
    int   xc0[PX_PER_THREAD], xc1[PX_PER_THREAD];
    bool  x0v[PX_PER_THREAD], x1v[PX_PER_THREAD];

#pragma unroll
    for (int k = 0; k < PX_PER_THREAD; ++k) {
        const float xs  = 2.0f * ((float)(ox + k) + 0.5f) / (float)W_OUT - 1.0f;
        const float gx  = s * xs + tx;
        const float ixf = ((gx + 1.0f) * (float)W_IN - 1.0f) * 0.5f;
        const float ix0f = floorf(ixf);
        wx1[k] = ixf - ix0f;
        wx0[k] = 1.0f - wx1[k];
        const int ix0 = (int)ix0f;
        const int ix1 = ix0 + 1;
        x0v[k] = (unsigned)ix0 < (unsigned)W_IN;
        x1v[k] = (unsigned)ix1 < (unsigned)W_IN;
        xc0[k] = min(max(ix0, 0), W_IN - 1);
        xc1[k] = min(max(ix1, 0), W_IN - 1);
    }

    float v00[PX_PER_THREAD], v01[PX_PER_THREAD];
    float v10[PX_PER_THREAD], v11[PX_PER_THREAD];
#pragma unroll
    for (int k = 0; k < PX_PER_THREAD; ++k) {
        v00[k] = r0[xc0[k]];
        v01[k] = r0[xc1[k]];
        v10[k] = r1[xc0[k]];
        v11[k] = r1[xc1[k]];
    }

    float4 res;
    float* resp = (float*)&res;
#pragma unroll
    for (int k = 0; k < PX_PER_THREAD; ++k) {
        const float a00 = (y0v && x0v[k]) ? v00[k] : 0.0f;
        const float a01 = (y0v && x1v[k]) ? v01[k] : 0.0f;
        const float a10 = (y1v && x0v[k]) ? v10[k] : 0.0f;
        const float a11 = (y1v && x1v[k]) ? v11[k] : 0.0f;
        resp[k] = wy0 * (wx0[k] * a00 + wx1[k] * a01) +
                  wy1 * (wx0[k] * a10 + wx1[k] * a11);
    }

    // p is a multiple of 4 -> 16B-aligned float4 store, fully coalesced
    *(float4*)(out + (size_t)b * PX_PER_IMG + p) = res;
}

extern "C" void kernel_launch(void* const* d_in, const int* in_sizes, int n_in,
                              void* d_out, int out_size, void* d_ws, size_t ws_size,
                              hipStream_t stream) {
    const float* x  = (const float*)d_in[0];
    const float* zw = (const float*)d_in[1];
    float* out = (float*)d_out;

    const int B = in_sizes[1] / 3;                    // 1024
    const int grid = B * BLOCKS_PER_IMG;              // 9216 blocks
    st_bilinear_x4_kernel<<<grid, BLOCK, 0, stream>>>(x, zw, out);
}

// Round 3
// 204.425 us; speedup vs baseline: 1.0600x; 1.0315x over previous
//
#include <hip/hip_runtime.h>

// Spatial transformer: affine grid (scale s, translate tx,ty) + bilinear
// sampling with zero padding.
//   x:       (1024, 1, 192, 192) f32
//   z_where: (1024, 3)           f32   [s, tx, ty]
//   out:     (1024, 1, 96, 96)   f32
//
// R3: column mapping — each thread owns one ox and 4 consecutive output rows:
//   * x-interpolation (ix0/ix1/wx/masks) computed ONCE per thread
//   * every tap-load instruction has lane-consecutive ox -> lane address
//     stride 2s*4B <= 8 B -> ~4 cache-line requests per instr (4x fewer TA
//     requests than R2's quad-per-thread mapping)
//   * grid algebra folded: ix = 2s*ox + (96*tx + 95.5 - 95*s)  (A,B uniform)
// Block = 192 threads (3 waves) = 8 rows; 12 blocks/image; b = blockIdx.y.

#define H_IN   192
#define W_IN   192
#define H_OUT  96
#define W_OUT  96
#define PX_PER_IMG      (H_OUT * W_OUT)     // 9216
#define BLOCK           192                 // 3 waves
#define ROWS_PER_THREAD 4
#define ROWS_PER_BLOCK  8                   // (192/96) * 4
#define BLOCKS_PER_IMG  (H_OUT / ROWS_PER_BLOCK)  // 12

__global__ __launch_bounds__(BLOCK) void st_bilinear_col_kernel(
    const float* __restrict__ x,
    const float* __restrict__ zw,
    float* __restrict__ out)
{
    const int b  = blockIdx.y;                       // image — block-uniform
    const int t  = threadIdx.x;
    const int ox = t % W_OUT;                        // 0..95
    const int oy0 = blockIdx.x * ROWS_PER_BLOCK + (t / W_OUT) * ROWS_PER_THREAD;

    // z_where — uniform per block -> scalar loads
    const float s  = zw[b * 3 + 0];
    const float tx = zw[b * 3 + 1];
    const float ty = zw[b * 3 + 2];

    // Folded grid transform (exact up to fp re-association, ~1e-5 px):
    //   ix = ((s*xs + tx + 1)*192 - 1)/2,  xs = (2*ox + 1)/96 - 1
    //      = 2s*ox + 96*tx + 95.5 - 95*s
    const float A  = 2.0f * s;
    const float C0 = fmaf(-95.0f, s, 95.5f);
    const float Bx = fmaf(96.0f, tx, C0);
    const float By = fmaf(96.0f, ty, C0);

    // ---- x side: once per thread ----
    const float ix   = fmaf(A, (float)ox, Bx);
    const float ix0f = floorf(ix);
    const float wx1  = ix - ix0f;
    const float wx0  = 1.0f - wx1;
    const int   ix0  = (int)ix0f;
    const int   ix1  = ix0 + 1;
    const bool  x0v  = (unsigned)ix0 < (unsigned)W_IN;
    const bool  x1v  = (unsigned)ix1 < (unsigned)W_IN;
    const int   xc0  = min(max(ix0, 0), W_IN - 1);
    const int   xc1  = min(max(ix1, 0), W_IN - 1);

    const float* __restrict__ img = x + (size_t)b * (H_IN * W_IN);
    float* __restrict__ op = out + (size_t)b * PX_PER_IMG + oy0 * W_OUT + ox;

    // ---- y side: 4 rows; compute indices first, then batch 16 loads ----
    float wy0[ROWS_PER_THREAD], wy1[ROWS_PER_THREAD];
    int   r0[ROWS_PER_THREAD], r1[ROWS_PER_THREAD];
    bool  y0v[ROWS_PER_THREAD], y1v[ROWS_PER_THREAD];

#pragma unroll
    for (int j = 0; j < ROWS_PER_THREAD; ++j) {
        const float iy   = fmaf(A, (float)(oy0 + j), By);
        const float iy0f = floorf(iy);
        wy1[j] = iy - iy0f;
        wy0[j] = 1.0f - wy1[j];
        const int iy0 = (int)iy0f;
        const int iy1 = iy0 + 1;
        y0v[j] = (unsigned)iy0 < (unsigned)H_IN;
        y1v[j] = (unsigned)iy1 < (unsigned)H_IN;
        r0[j] = min(max(iy0, 0), H_IN - 1) * W_IN;
        r1[j] = min(max(iy1, 0), H_IN - 1) * W_IN;
    }

    float v00[ROWS_PER_THREAD], v01[ROWS_PER_THREAD];
    float v10[ROWS_PER_THREAD], v11[ROWS_PER_THREAD];
#pragma unroll
    for (int j = 0; j < ROWS_PER_THREAD; ++j) {
        v00[j] = img[r0[j] + xc0];
        v01[j] = img[r0[j] + xc1];
        v10[j] = img[r1[j] + xc0];
        v11[j] = img[r1[j] + xc1];
    }

#pragma unroll
    for (int j = 0; j < ROWS_PER_THREAD; ++j) {
        const float a00 = (y0v[j] && x0v) ? v00[j] : 0.0f;
        const float a01 = (y0v[j] && x1v) ? v01[j] : 0.0f;
        const float a10 = (y1v[j] && x0v) ? v10[j] : 0.0f;
        const float a11 = (y1v[j] && x1v) ? v11[j] : 0.0f;
        const float h0 = wx0 * a00 + wx1 * a01;
        const float h1 = wx0 * a10 + wx1 * a11;
        op[j * W_OUT] = wy0[j] * h0 + wy1[j] * h1;   // lanes: consecutive ox
    }
}

extern "C" void kernel_launch(void* const* d_in, const int* in_sizes, int n_in,
                              void* d_out, int out_size, void* d_ws, size_t ws_size,
                              hipStream_t stream) {
    const float* x  = (const float*)d_in[0];
    const float* zw = (const float*)d_in[1];
    float* out = (float*)d_out;

    const int B = in_sizes[1] / 3;                    // 1024
    dim3 grid(BLOCKS_PER_IMG, B);                     // (12, 1024)
    st_bilinear_col_kernel<<<grid, BLOCK, 0, stream>>>(x, zw, out);
}